// Round 4
// baseline (2160.450 us; speedup 1.0000x reference)
//
#include <hip/hip_runtime.h>
#include <hip/hip_bf16.h>

#define D_INc 256
#define D_KQc 512
#define D_Vc 64
#define NHh 8
#define TDIMc 512
#define NBb 8
#define Sc 1024
#define EPSV 1e-5f

// ---------------- K1: temb = relu(t @ Wt + bt)  [8,256] ----------------
__global__ __launch_bounds__(256) void k_temb(const float* __restrict__ t,
        const float* __restrict__ Wt, const float* __restrict__ bt,
        float* __restrict__ temb) {
    __shared__ float tl[TDIMc];
    int n = blockIdx.x, c = threadIdx.x;
    tl[c] = t[n*TDIMc + c];
    tl[c+256] = t[n*TDIMc + c + 256];
    __syncthreads();
    float acc = bt[c];
    #pragma unroll 8
    for (int i = 0; i < TDIMc; i++) acc += tl[i] * Wt[i*D_INc + c];
    temb[n*D_INc + c] = fmaxf(acc, 0.f);
}

// ---------------- K2: BN stats -> a[c], off[n][c] ----------------
__global__ __launch_bounds__(256) void k_stats(const float* __restrict__ x,
        const float* __restrict__ temb, const float* __restrict__ gamma,
        const float* __restrict__ beta, float* __restrict__ aArr,
        float* __restrict__ offArr) {
    int c = blockIdx.x, t = threadIdx.x;
    __shared__ float wred[4];
    __shared__ float snA[NBb];
    float sq = 0.f;
    for (int n = 0; n < NBb; n++) {
        const float4 v = reinterpret_cast<const float4*>(x + (size_t)(n*D_INc + c)*Sc)[t];
        float s = v.x + v.y + v.z + v.w;
        sq += v.x*v.x + v.y*v.y + v.z*v.z + v.w*v.w;
        for (int msk = 32; msk >= 1; msk >>= 1) s += __shfl_xor(s, msk);
        if ((t & 63) == 0) wred[t >> 6] = s;
        __syncthreads();
        if (t == 0) snA[n] = wred[0] + wred[1] + wred[2] + wred[3];
        __syncthreads();
    }
    for (int msk = 32; msk >= 1; msk >>= 1) sq += __shfl_xor(sq, msk);
    if ((t & 63) == 0) wred[t >> 6] = sq;
    __syncthreads();
    if (t == 0) {
        float sumsq = wred[0]+wred[1]+wred[2]+wred[3];
        float sumx = 0.f, tsum = 0.f, tsq = 0.f, cross = 0.f;
        for (int n = 0; n < NBb; n++) {
            float tv = temb[n*D_INc + c];
            sumx += snA[n]; tsum += tv; tsq += tv*tv; cross += tv*snA[n];
        }
        const float inv = 1.f / (float)(NBb * Sc);
        float mean = (sumx + (float)Sc * tsum) * inv;
        float ex2  = (sumsq + 2.f*cross + (float)Sc * tsq) * inv;
        float var  = ex2 - mean*mean;
        float a = gamma[c] * rsqrtf(var + EPSV);
        aArr[c] = a;
        float b = beta[c];
        for (int n = 0; n < NBb; n++)
            offArr[n*D_INc + c] = (temb[n*D_INc + c] - mean) * a + b;
    }
}

// ---------------- K3: weight prep (f32 transposed copies) ----------------
// wqkvt[j][c]: j<512 Wq; 512..1023 Wk; 1024..1087 Wv  (all [c][j] -> [j][c])
// wpt[cout][j'], j' = h*64+dv  ->  Wp[dv*8+h][cout]   (absorbs reshape interleave)
__global__ __launch_bounds__(256) void k_prepw32(const float* __restrict__ Wq,
        const float* __restrict__ Wk, const float* __restrict__ Wv,
        const float* __restrict__ Wp,
        float* __restrict__ wqkvt, float* __restrict__ wpt) {
    int b = blockIdx.x, t = threadIdx.x;
    if (b < 1088) {
        float v;
        if (b < 512) v = Wq[t*D_KQc + b];
        else if (b < 1024) v = Wk[t*D_KQc + (b-512)];
        else v = Wv[t*D_Vc + (b-1024)];
        wqkvt[b*D_INc + t] = v;
    } else {
        int cout = b - 1088;
        for (int j = t; j < 512; j += 256) {
            int r = (j & 63)*8 + (j >> 6);
            wpt[cout*512 + j] = Wp[r*D_INc + cout];
        }
    }
}

// ---------------- K4: Xs[n][s][c] = x[n][c][s]*a[c] + off[n][c]  (f32, transposed) ----------------
__global__ __launch_bounds__(256) void k_xs32(const float* __restrict__ x,
        const float* __restrict__ aArr, const float* __restrict__ offArr,
        float* __restrict__ xs) {
    __shared__ float tile[64][65];
    int s0 = blockIdx.x * 64, c0 = blockIdx.y * 64, n = blockIdx.z;
    int t = threadIdx.x;
    #pragma unroll
    for (int p = 0; p < 16; p++) {
        int idx = p*256 + t;
        int cl = idx >> 6, sl = idx & 63;
        int c = c0 + cl;
        tile[cl][sl] = x[((size_t)n*D_INc + c)*Sc + s0 + sl] * aArr[c] + offArr[n*D_INc + c];
    }
    __syncthreads();
    #pragma unroll
    for (int p = 0; p < 16; p++) {
        int idx = p*256 + t;
        int sl = idx >> 6, cl = idx & 63;
        xs[((size_t)(n*Sc + s0 + sl))*D_INc + c0 + cl] = tile[cl][sl];
    }
}

// ---------------- K5: QKV f32 GEMM. C[s][j] = Xs[s][:].wqkvt[j][:] ----------------
// j<512 -> qbuf[n][s][j] ; 512..1023 -> kt[n][j-512][s] ; >=1024 -> vt[n][j-1024][s]
__global__ __launch_bounds__(256) void k_qkv32(const float* __restrict__ xs,
        const float* __restrict__ wq, float* __restrict__ qbuf,
        float* __restrict__ kt, float* __restrict__ vt) {
    __shared__ float As[64][17], Bs[64][17];
    int jt = blockIdx.x, st = blockIdx.y, n = blockIdx.z;
    int t = threadIdx.x, tx = t & 15, ty = t >> 4;
    int s0 = st*64, j0 = jt*64;
    float acc[4][4] = {};
    for (int k0 = 0; k0 < 256; k0 += 16) {
        #pragma unroll
        for (int p = 0; p < 4; p++) {
            int idx = p*256 + t;
            int row = idx >> 4, kk = idx & 15;
            As[row][kk] = xs[((size_t)(n*Sc + s0 + row))*D_INc + k0 + kk];
            Bs[row][kk] = wq[((size_t)(j0 + row))*D_INc + k0 + kk];
        }
        __syncthreads();
        #pragma unroll
        for (int kk = 0; kk < 16; kk++) {
            float a[4], b[4];
            #pragma unroll
            for (int i = 0; i < 4; i++) a[i] = As[ty + 16*i][kk];
            #pragma unroll
            for (int j = 0; j < 4; j++) b[j] = Bs[tx + 16*j][kk];
            #pragma unroll
            for (int i = 0; i < 4; i++)
                #pragma unroll
                for (int j = 0; j < 4; j++) acc[i][j] += a[i]*b[j];
        }
        __syncthreads();
    }
    #pragma unroll
    for (int i = 0; i < 4; i++) {
        int s = s0 + ty + 16*i;
        #pragma unroll
        for (int j = 0; j < 4; j++) {
            int jj = j0 + tx + 16*j;
            float c = acc[i][j];
            if (j0 < 512)       qbuf[((size_t)(n*Sc + s))*512 + jj] = c;
            else if (j0 < 1024) kt[((size_t)(n*D_KQc + jj - 512))*Sc + s] = c;
            else                vt[((size_t)(n*D_Vc + jj - 1024))*Sc + s] = c;
        }
    }
}

// ---------------- K6: f32 attention, one block per (n, head, 16-q tile) ----------------
// slds holds all 1024 scores per q (64KB LDS): 2-pass exact softmax, then P.V
__global__ __launch_bounds__(256) void k_attn32(const float* __restrict__ qbuf,
        const float* __restrict__ kt, const float* __restrict__ vt,
        float* __restrict__ obuf) {
    __shared__ float slds[16][1025];
    __shared__ float qlds[16][64];
    __shared__ float mred[16], sred[16];
    int qt = blockIdx.x, h = blockIdx.y, n = blockIdx.z;
    int t = threadIdx.x;
    int q0 = qt*16;
    #pragma unroll
    for (int p = 0; p < 4; p++) {
        int idx = p*256 + t;
        int q = idx >> 6, d = idx & 63;
        qlds[q][d] = qbuf[((size_t)(n*Sc + q0 + q))*512 + h*64 + d];
    }
    __syncthreads();
    const float scale = 0.044194173824159216f; // 1/sqrt(512)
    // pass 1: scores (thread t = key within 256-chunk)
    for (int kc = 0; kc < 4; kc++) {
        int k0 = kc*256;
        float sc[16];
        #pragma unroll
        for (int q = 0; q < 16; q++) sc[q] = 0.f;
        const float* kp = kt + ((size_t)(n*D_KQc + h*64))*Sc + k0 + t;
        for (int d = 0; d < 64; d++) {
            float kv = kp[(size_t)d*Sc];
            #pragma unroll
            for (int q = 0; q < 16; q++) sc[q] += kv * qlds[q][d];
        }
        #pragma unroll
        for (int q = 0; q < 16; q++) slds[q][k0 + t] = sc[q] * scale;
    }
    __syncthreads();
    // pass 2: per-q max (16 lanes per q)
    {
        int q = t >> 4, l16 = t & 15;
        float m = -1e30f;
        for (int s = l16; s < 1024; s += 16) m = fmaxf(m, slds[q][s]);
        #pragma unroll
        for (int msk = 8; msk >= 1; msk >>= 1) m = fmaxf(m, __shfl_xor(m, msk));
        if (l16 == 0) mred[q] = m;
    }
    __syncthreads();
    // pass 3: exponentiate + per-q sum
    {
        int q = t >> 4, l16 = t & 15;
        float m = mred[q], acc = 0.f;
        for (int s = l16; s < 1024; s += 16) {
            float e = __expf(slds[q][s] - m);
            slds[q][s] = e;
            acc += e;
        }
        #pragma unroll
        for (int msk = 8; msk >= 1; msk >>= 1) acc += __shfl_xor(acc, msk);
        if (l16 == 0) sred[q] = acc;
    }
    __syncthreads();
    // pass 4: out[q][dv] = (sum_s P v) / sum  (thread t -> q = t>>4, dv = (t&15)*4 .. +3)
    {
        int q = t >> 4, dv0 = (t & 15) * 4;
        float acc0=0.f, acc1=0.f, acc2=0.f, acc3=0.f;
        const float* vp = vt + ((size_t)(n*D_Vc + dv0))*Sc;
        for (int s = 0; s < 1024; s++) {
            float p = slds[q][s];
            acc0 += p * vp[s];
            acc1 += p * vp[Sc + s];
            acc2 += p * vp[2*Sc + s];
            acc3 += p * vp[3*Sc + s];
        }
        float inv = 1.f / sred[q];
        size_t ob = ((size_t)(n*Sc + q0 + q))*512 + h*64 + dv0;
        obuf[ob+0] = acc0*inv; obuf[ob+1] = acc1*inv;
        obuf[ob+2] = acc2*inv; obuf[ob+3] = acc3*inv;
    }
}

// ---------------- K7: out[n][c][s] = obuf[s][:].wpt[c][:] + bp[c] + x[n][c][s] ----------------
__global__ __launch_bounds__(256) void k_proj32(const float* __restrict__ obuf,
        const float* __restrict__ wpt, const float* __restrict__ bp,
        const float* __restrict__ x, float* __restrict__ out) {
    __shared__ float As[64][17], Bs[64][17];
    int st = blockIdx.x, ct = blockIdx.y, n = blockIdx.z;
    int t = threadIdx.x, tx = t & 15, ty = t >> 4;
    int s0 = st*64, c0 = ct*64;
    float acc[4][4] = {};
    for (int k0 = 0; k0 < 512; k0 += 16) {
        #pragma unroll
        for (int p = 0; p < 4; p++) {
            int idx = p*256 + t;
            int row = idx >> 4, kk = idx & 15;
            As[row][kk] = wpt[((size_t)(c0 + row))*512 + k0 + kk];
            Bs[row][kk] = obuf[((size_t)(n*Sc + s0 + row))*512 + k0 + kk];
        }
        __syncthreads();
        #pragma unroll
        for (int kk = 0; kk < 16; kk++) {
            float a[4], b[4];
            #pragma unroll
            for (int i = 0; i < 4; i++) a[i] = As[ty + 16*i][kk];
            #pragma unroll
            for (int j = 0; j < 4; j++) b[j] = Bs[tx + 16*j][kk];
            #pragma unroll
            for (int i = 0; i < 4; i++)
                #pragma unroll
                for (int j = 0; j < 4; j++) acc[i][j] += a[i]*b[j];
        }
        __syncthreads();
    }
    #pragma unroll
    for (int i = 0; i < 4; i++) {
        int c = c0 + ty + 16*i;
        #pragma unroll
        for (int j = 0; j < 4; j++) {
            int s = s0 + tx + 16*j;
            size_t idx = ((size_t)n*D_INc + c)*Sc + s;
            out[idx] = acc[i][j] + bp[c] + x[idx];
        }
    }
}

extern "C" void kernel_launch(void* const* d_in, const int* in_sizes, int n_in,
                              void* d_out, int out_size, void* d_ws, size_t ws_size,
                              hipStream_t stream) {
    const float* x     = (const float*)d_in[0];
    const float* t     = (const float*)d_in[1];
    const float* Wt    = (const float*)d_in[2];
    const float* bt    = (const float*)d_in[3];
    const float* Wq    = (const float*)d_in[4];
    const float* Wk    = (const float*)d_in[5];
    const float* Wv    = (const float*)d_in[6];
    const float* Wp    = (const float*)d_in[7];
    const float* bp    = (const float*)d_in[8];
    const float* gamma = (const float*)d_in[9];
    const float* beta  = (const float*)d_in[10];
    char* ws = (char*)d_ws;
    float* temb  = (float*)(ws + 0);               // 8 KB
    float* aArr  = (float*)(ws + 8192);            // 1 KB
    float* offA  = (float*)(ws + 9216);            // 8 KB
    float* wqkvt = (float*)(ws + 32768);           // 1.06 MB [1088][256] f32
    float* wpt   = (float*)(ws + 1179648);         // 512 KB  [256][512] f32
    float* xs    = (float*)(ws + 2097152);         // 8 MB    [8][1024][256] f32
    float* qbuf  = (float*)(ws + 10485760);        // 16 MB   [8][1024][512] f32
    float* kt    = (float*)(ws + 27262976);        // 16 MB   [8][512][1024] f32
    float* vt    = (float*)(ws + 44040192);        // 2 MB    [8][64][1024] f32
    float* obuf  = (float*)(ws + 46137344);        // 16 MB   [8][1024][512] f32
    float* out = (float*)d_out;

    hipLaunchKernelGGL(k_temb,   dim3(8),        dim3(256), 0, stream, t, Wt, bt, temb);
    hipLaunchKernelGGL(k_stats,  dim3(256),      dim3(256), 0, stream, x, temb, gamma, beta, aArr, offA);
    hipLaunchKernelGGL(k_prepw32,dim3(1344),     dim3(256), 0, stream, Wq, Wk, Wv, Wp, wqkvt, wpt);
    hipLaunchKernelGGL(k_xs32,   dim3(16,4,8),   dim3(256), 0, stream, x, aArr, offA, xs);
    hipLaunchKernelGGL(k_qkv32,  dim3(17,16,8),  dim3(256), 0, stream, xs, wqkvt, qbuf, kt, vt);
    hipLaunchKernelGGL(k_attn32, dim3(64,8,8),   dim3(256), 0, stream, qbuf, kt, vt, obuf);
    hipLaunchKernelGGL(k_proj32, dim3(16,4,8),   dim3(256), 0, stream, obuf, wpt, bp, x, out);
}

// Round 5
// 297.638 us; speedup vs baseline: 7.2587x; 7.2587x over previous
//
#include <hip/hip_runtime.h>
#include <hip/hip_bf16.h>

#define D_INc 256
#define D_KQc 512
#define D_Vc 64
#define NHh 8
#define TDIMc 512
#define NBb 8
#define Sc 1024
#define EPSV 1e-5f

typedef __bf16 bf16x8 __attribute__((ext_vector_type(8)));
typedef float f32x4 __attribute__((ext_vector_type(4)));

// ---------------- K1: temb = relu(t @ Wt + bt)  [8,256] ----------------
__global__ __launch_bounds__(256) void k_temb(const float* __restrict__ t,
        const float* __restrict__ Wt, const float* __restrict__ bt,
        float* __restrict__ temb) {
    __shared__ float tl[TDIMc];
    int n = blockIdx.x, c = threadIdx.x;
    tl[c] = t[n*TDIMc + c];
    tl[c+256] = t[n*TDIMc + c + 256];
    __syncthreads();
    float acc = bt[c];
    #pragma unroll 8
    for (int i = 0; i < TDIMc; i++) acc += tl[i] * Wt[i*D_INc + c];
    temb[n*D_INc + c] = fmaxf(acc, 0.f);
}

// ---------------- K2: BN stats -> a[c], off[n][c] ----------------
__global__ __launch_bounds__(256) void k_stats(const float* __restrict__ x,
        const float* __restrict__ temb, const float* __restrict__ gamma,
        const float* __restrict__ beta, float* __restrict__ aArr,
        float* __restrict__ offArr) {
    int c = blockIdx.x, t = threadIdx.x;
    __shared__ float wred[4];
    __shared__ float snA[NBb];
    float sq = 0.f;
    for (int n = 0; n < NBb; n++) {
        const float4 v = reinterpret_cast<const float4*>(x + (size_t)(n*D_INc + c)*Sc)[t];
        float s = v.x + v.y + v.z + v.w;
        sq += v.x*v.x + v.y*v.y + v.z*v.z + v.w*v.w;
        for (int msk = 32; msk >= 1; msk >>= 1) s += __shfl_xor(s, msk);
        if ((t & 63) == 0) wred[t >> 6] = s;
        __syncthreads();
        if (t == 0) snA[n] = wred[0] + wred[1] + wred[2] + wred[3];
        __syncthreads();
    }
    for (int msk = 32; msk >= 1; msk >>= 1) sq += __shfl_xor(sq, msk);
    if ((t & 63) == 0) wred[t >> 6] = sq;
    __syncthreads();
    if (t == 0) {
        float sumsq = wred[0]+wred[1]+wred[2]+wred[3];
        float sumx = 0.f, tsum = 0.f, tsq = 0.f, cross = 0.f;
        for (int n = 0; n < NBb; n++) {
            float tv = temb[n*D_INc + c];
            sumx += snA[n]; tsum += tv; tsq += tv*tv; cross += tv*snA[n];
        }
        const float inv = 1.f / (float)(NBb * Sc);
        float mean = (sumx + (float)Sc * tsum) * inv;
        float ex2  = (sumsq + 2.f*cross + (float)Sc * tsq) * inv;
        float var  = ex2 - mean*mean;
        float a = gamma[c] * rsqrtf(var + EPSV);
        aArr[c] = a;
        float b = beta[c];
        for (int n = 0; n < NBb; n++)
            offArr[n*D_INc + c] = (temb[n*D_INc + c] - mean) * a + b;
    }
}

// ---------------- K3: weight prep (f32 transposed copies) ----------------
__global__ __launch_bounds__(256) void k_prepw32(const float* __restrict__ Wq,
        const float* __restrict__ Wk, const float* __restrict__ Wv,
        const float* __restrict__ Wp,
        float* __restrict__ wqkvt, float* __restrict__ wpt) {
    int b = blockIdx.x, t = threadIdx.x;
    if (b < 1088) {
        float v;
        if (b < 512) v = Wq[t*D_KQc + b];
        else if (b < 1024) v = Wk[t*D_KQc + (b-512)];
        else v = Wv[t*D_Vc + (b-1024)];
        wqkvt[b*D_INc + t] = v;
    } else {
        int cout = b - 1088;
        for (int j = t; j < 512; j += 256) {
            int r = (j & 63)*8 + (j >> 6);
            wpt[cout*512 + j] = Wp[r*D_INc + cout];
        }
    }
}

// ---------------- K4: Xs[n][s][c] = x[n][c][s]*a[c] + off[n][c]  (f32, transposed) ----------------
__global__ __launch_bounds__(256) void k_xs32(const float* __restrict__ x,
        const float* __restrict__ aArr, const float* __restrict__ offArr,
        float* __restrict__ xs) {
    __shared__ float tile[64][65];
    int s0 = blockIdx.x * 64, c0 = blockIdx.y * 64, n = blockIdx.z;
    int t = threadIdx.x;
    #pragma unroll
    for (int p = 0; p < 16; p++) {
        int idx = p*256 + t;
        int cl = idx >> 6, sl = idx & 63;
        int c = c0 + cl;
        tile[cl][sl] = x[((size_t)n*D_INc + c)*Sc + s0 + sl] * aArr[c] + offArr[n*D_INc + c];
    }
    __syncthreads();
    #pragma unroll
    for (int p = 0; p < 16; p++) {
        int idx = p*256 + t;
        int sl = idx >> 6, cl = idx & 63;
        xs[((size_t)(n*Sc + s0 + sl))*D_INc + c0 + cl] = tile[cl][sl];
    }
}

// ---------------- K5: QKV f32 GEMM -> bf16 q/k/v. C[s][j] = Xs[s][:].wqkvt[j][:] ----------------
// j<512 -> qb[n][s][j] ; 512..1023 -> kb[n][s][j-512] ; >=1024 -> vb[n][j-1024][s] (V^T)
__global__ __launch_bounds__(256) void k_qkv32(const float* __restrict__ xs,
        const float* __restrict__ wq, __hip_bfloat16* __restrict__ qb,
        __hip_bfloat16* __restrict__ kb, __hip_bfloat16* __restrict__ vb) {
    __shared__ float As[64][17], Bs[64][17];
    int jt = blockIdx.x, st = blockIdx.y, n = blockIdx.z;
    int t = threadIdx.x, tx = t & 15, ty = t >> 4;
    int s0 = st*64, j0 = jt*64;
    float acc[4][4] = {};
    for (int k0 = 0; k0 < 256; k0 += 16) {
        #pragma unroll
        for (int p = 0; p < 4; p++) {
            int idx = p*256 + t;
            int row = idx >> 4, kk = idx & 15;
            As[row][kk] = xs[((size_t)(n*Sc + s0 + row))*D_INc + k0 + kk];
            Bs[row][kk] = wq[((size_t)(j0 + row))*D_INc + k0 + kk];
        }
        __syncthreads();
        #pragma unroll
        for (int kk = 0; kk < 16; kk++) {
            float a[4], b[4];
            #pragma unroll
            for (int i = 0; i < 4; i++) a[i] = As[ty + 16*i][kk];
            #pragma unroll
            for (int j = 0; j < 4; j++) b[j] = Bs[tx + 16*j][kk];
            #pragma unroll
            for (int i = 0; i < 4; i++)
                #pragma unroll
                for (int j = 0; j < 4; j++) acc[i][j] += a[i]*b[j];
        }
        __syncthreads();
    }
    #pragma unroll
    for (int i = 0; i < 4; i++) {
        int s = s0 + ty + 16*i;
        #pragma unroll
        for (int j = 0; j < 4; j++) {
            int jj = j0 + tx + 16*j;
            float c = acc[i][j];
            if (j0 < 512)       qb[((size_t)(n*Sc + s))*512 + jj] = __float2bfloat16(c);
            else if (j0 < 1024) kb[((size_t)(n*Sc + s))*512 + (jj-512)] = __float2bfloat16(c);
            else                vb[((size_t)(n*D_Vc + (jj-1024)))*Sc + s] = __float2bfloat16(c);
        }
    }
}

// ---------------- K6: MFMA attention per (n, head, 64-q block); f32 out ----------------
// S^T = mfma(K, Q): lane(lr,lg) holds S[q=lr][key=k0+{lg*4+r | 16+lg*4+r}].
// P staged in LDS as plds[w][q][key_local]; PV: O^T = mfma(V^T, P).
__global__ __launch_bounds__(256) void k_attn_mfma(const __hip_bfloat16* __restrict__ qb,
        const __hip_bfloat16* __restrict__ kb, const __hip_bfloat16* __restrict__ vb,
        float* __restrict__ obuf) {
    __shared__ __hip_bfloat16 plds[4][16][32];   // [wave][q][key_local]
    __shared__ float olds[4][16][68];            // [wave][q][dv]
    int qt = blockIdx.x, h = blockIdx.y, n = blockIdx.z;
    int t = threadIdx.x, w = t >> 6, l = t & 63;
    int lr = l & 15, lg = l >> 4;
    int q0 = qt*64 + w*16;
    const float scale = 0.044194173824159216f; // 1/sqrt(512)
    const __hip_bfloat16* qrow = qb + ((size_t)(n*Sc + q0 + lr))*512 + h*64 + lg*8;
    bf16x8 qf0 = *reinterpret_cast<const bf16x8*>(qrow);
    bf16x8 qf1 = *reinterpret_cast<const bf16x8*>(qrow + 32);
    const __hip_bfloat16* kbase = kb + (size_t)n*Sc*512 + h*64 + lg*8;
    const __hip_bfloat16* vbase = vb + (size_t)n*D_Vc*Sc + lg*8;
    float m = -1e30f, lsum = 0.f;
    f32x4 oacc[4] = {};
    for (int kc = 0; kc < 32; kc++) {
        int k0 = kc*32;
        f32x4 sa0 = {}, sa1 = {};
        {
            const __hip_bfloat16* kr0 = kbase + (size_t)(k0 + lr)*512;
            const __hip_bfloat16* kr1 = kr0 + 16*512;
            bf16x8 ka = *reinterpret_cast<const bf16x8*>(kr0);
            bf16x8 kbv = *reinterpret_cast<const bf16x8*>(kr0 + 32);
            bf16x8 kc2 = *reinterpret_cast<const bf16x8*>(kr1);
            bf16x8 kd = *reinterpret_cast<const bf16x8*>(kr1 + 32);
            sa0 = __builtin_amdgcn_mfma_f32_16x16x32_bf16(ka,  qf0, sa0, 0,0,0);
            sa0 = __builtin_amdgcn_mfma_f32_16x16x32_bf16(kbv, qf1, sa0, 0,0,0);
            sa1 = __builtin_amdgcn_mfma_f32_16x16x32_bf16(kc2, qf0, sa1, 0,0,0);
            sa1 = __builtin_amdgcn_mfma_f32_16x16x32_bf16(kd,  qf1, sa1, 0,0,0);
        }
        float sv[8];
        #pragma unroll
        for (int r = 0; r < 4; r++) { sv[r] = sa0[r]*scale; sv[4+r] = sa1[r]*scale; }
        float cmax = sv[0];
        #pragma unroll
        for (int i = 1; i < 8; i++) cmax = fmaxf(cmax, sv[i]);
        cmax = fmaxf(cmax, __shfl_xor(cmax, 16));
        cmax = fmaxf(cmax, __shfl_xor(cmax, 32));
        float mnew = fmaxf(m, cmax);
        float sf = __expf(m - mnew);
        float p[8], csum = 0.f;
        #pragma unroll
        for (int i = 0; i < 8; i++) { p[i] = __expf(sv[i] - mnew); csum += p[i]; }
        csum += __shfl_xor(csum, 16);
        csum += __shfl_xor(csum, 32);
        lsum = lsum*sf + csum;
        m = mnew;
        #pragma unroll
        for (int mt = 0; mt < 4; mt++)
            #pragma unroll
            for (int r = 0; r < 4; r++) oacc[mt][r] *= sf;
        // stage P: lane(lr,lg) owns S[q=lr][keys lg*4+r and 16+lg*4+r]
        #pragma unroll
        for (int r = 0; r < 4; r++) {
            plds[w][lr][lg*4 + r]      = __float2bfloat16(p[r]);
            plds[w][lr][16 + lg*4 + r] = __float2bfloat16(p[4 + r]);
        }
        __syncthreads();
        // B-frag for PV: lane(lr,lg) needs P[key=lg*8+j][q=lr] = plds[w][lr][lg*8+j]
        bf16x8 pb = *reinterpret_cast<const bf16x8*>(&plds[w][lr][lg*8]);
        #pragma unroll
        for (int mt = 0; mt < 4; mt++) {
            bf16x8 vf = *reinterpret_cast<const bf16x8*>(vbase + (size_t)(mt*16 + lr)*Sc + k0);
            oacc[mt] = __builtin_amdgcn_mfma_f32_16x16x32_bf16(vf, pb, oacc[mt], 0,0,0);
        }
        __syncthreads();
    }
    float inv = 1.f / lsum;
    #pragma unroll
    for (int mt = 0; mt < 4; mt++)
        #pragma unroll
        for (int r = 0; r < 4; r++)
            olds[w][lr][mt*16 + lg*4 + r] = oacc[mt][r] * inv;
    __syncthreads();
    // write 16q x 64dv per wave: lane l -> q=l>>2, dv = (l&3)*16 + c*4
    int ql = l >> 2, dvb = (l & 3) * 16;
    float* op = obuf + ((size_t)(n*Sc + qt*64 + w*16 + ql))*512 + h*64 + dvb;
    #pragma unroll
    for (int c = 0; c < 4; c++) {
        float4 vv = *reinterpret_cast<const float4*>(&olds[w][ql][dvb + c*4]);
        *reinterpret_cast<float4*>(op + c*4) = vv;
    }
}

// ---------------- K7: out[n][c][s] = obuf[s][:].wpt[c][:] + bp[c] + x[n][c][s] ----------------
__global__ __launch_bounds__(256) void k_proj32(const float* __restrict__ obuf,
        const float* __restrict__ wpt, const float* __restrict__ bp,
        const float* __restrict__ x, float* __restrict__ out) {
    __shared__ float As[64][17], Bs[64][17];
    int st = blockIdx.x, ct = blockIdx.y, n = blockIdx.z;
    int t = threadIdx.x, tx = t & 15, ty = t >> 4;
    int s0 = st*64, c0 = ct*64;
    float acc[4][4] = {};
    for (int k0 = 0; k0 < 512; k0 += 16) {
        #pragma unroll
        for (int p = 0; p < 4; p++) {
            int idx = p*256 + t;
            int row = idx >> 4, kk = idx & 15;
            As[row][kk] = wpt[((size_t)(c0 + row))*512 + k0 + kk];
            Bs[row][kk] = obuf[((size_t)(n*Sc + s0 + row))*512 + k0 + kk];
        }
        __syncthreads();
        #pragma unroll
        for (int kk = 0; kk < 16; kk++) {
            float a[4], b[4];
            #pragma unroll
            for (int i = 0; i < 4; i++) a[i] = As[ty + 16*i][kk];
            #pragma unroll
            for (int j = 0; j < 4; j++) b[j] = Bs[tx + 16*j][kk];
            #pragma unroll
            for (int i = 0; i < 4; i++)
                #pragma unroll
                for (int j = 0; j < 4; j++) acc[i][j] += a[i]*b[j];
        }
        __syncthreads();
    }
    #pragma unroll
    for (int i = 0; i < 4; i++) {
        int c = c0 + ty + 16*i;
        #pragma unroll
        for (int j = 0; j < 4; j++) {
            int s = s0 + tx + 16*j;
            size_t idx = ((size_t)n*D_INc + c)*Sc + s;
            out[idx] = acc[i][j] + bp[c] + x[idx];
        }
    }
}

extern "C" void kernel_launch(void* const* d_in, const int* in_sizes, int n_in,
                              void* d_out, int out_size, void* d_ws, size_t ws_size,
                              hipStream_t stream) {
    const float* x     = (const float*)d_in[0];
    const float* t     = (const float*)d_in[1];
    const float* Wt    = (const float*)d_in[2];
    const float* bt    = (const float*)d_in[3];
    const float* Wq    = (const float*)d_in[4];
    const float* Wk    = (const float*)d_in[5];
    const float* Wv    = (const float*)d_in[6];
    const float* Wp    = (const float*)d_in[7];
    const float* bp    = (const float*)d_in[8];
    const float* gamma = (const float*)d_in[9];
    const float* beta  = (const float*)d_in[10];
    char* ws = (char*)d_ws;
    float* temb  = (float*)(ws + 0);               // 8 KB
    float* aArr  = (float*)(ws + 8192);            // 1 KB
    float* offA  = (float*)(ws + 9216);            // 8 KB
    float* wqkvt = (float*)(ws + 32768);           // 1.06 MB [1088][256] f32
    float* wpt   = (float*)(ws + 1179648);         // 512 KB  [256][512] f32
    float* xs    = (float*)(ws + 2097152);         // 8 MB    [8][1024][256] f32
    __hip_bfloat16* qb = (__hip_bfloat16*)(ws + 10485760);  // 8 MB [8][1024][512] bf16
    __hip_bfloat16* kb = (__hip_bfloat16*)(ws + 18874368);  // 8 MB [8][1024][512] bf16
    __hip_bfloat16* vb = (__hip_bfloat16*)(ws + 27262976);  // 1 MB [8][64][1024] bf16
    float* obuf  = (float*)(ws + 28311552);        // 16 MB   [8][1024][512] f32
    float* out = (float*)d_out;

    hipLaunchKernelGGL(k_temb,     dim3(8),        dim3(256), 0, stream, t, Wt, bt, temb);
    hipLaunchKernelGGL(k_stats,    dim3(256),      dim3(256), 0, stream, x, temb, gamma, beta, aArr, offA);
    hipLaunchKernelGGL(k_prepw32,  dim3(1344),     dim3(256), 0, stream, Wq, Wk, Wv, Wp, wqkvt, wpt);
    hipLaunchKernelGGL(k_xs32,     dim3(16,4,8),   dim3(256), 0, stream, x, aArr, offA, xs);
    hipLaunchKernelGGL(k_qkv32,    dim3(17,16,8),  dim3(256), 0, stream, xs, wqkvt, qb, kb, vb);
    hipLaunchKernelGGL(k_attn_mfma,dim3(16,8,8),   dim3(256), 0, stream, qb, kb, vb, obuf);
    hipLaunchKernelGGL(k_proj32,   dim3(16,4,8),   dim3(256), 0, stream, obuf, wpt, bp, x, out);
}

// Round 6
// 224.020 us; speedup vs baseline: 9.6440x; 1.3286x over previous
//
#include <hip/hip_runtime.h>
#include <hip/hip_bf16.h>

#define D_INc 256
#define D_KQc 512
#define D_Vc 64
#define NBb 8
#define Sc 1024
#define TDIMc 512
#define EPSV 1e-5f

typedef __bf16 bf16x8 __attribute__((ext_vector_type(8)));
typedef float f32x4 __attribute__((ext_vector_type(4)));

__device__ inline unsigned short f2bf(float f) {
    return __builtin_bit_cast(unsigned short, __float2bfloat16(f));
}
__device__ inline unsigned int pack2(float a, float b) {
    return (unsigned int)f2bf(a) | ((unsigned int)f2bf(b) << 16);
}

// ---------------- K1: temb = relu(t @ Wt + bt)  [8,256]  (verified) ----------------
__global__ __launch_bounds__(256) void k_temb(const float* __restrict__ t,
        const float* __restrict__ Wt, const float* __restrict__ bt,
        float* __restrict__ temb) {
    __shared__ float tl[TDIMc];
    int n = blockIdx.x, c = threadIdx.x;
    tl[c] = t[n*TDIMc + c];
    tl[c+256] = t[n*TDIMc + c + 256];
    __syncthreads();
    float acc = bt[c];
    #pragma unroll 8
    for (int i = 0; i < TDIMc; i++) acc += tl[i] * Wt[i*D_INc + c];
    temb[n*D_INc + c] = fmaxf(acc, 0.f);
}

// ---------------- K2: BN stats -> a[c], off[n][c]  (verified) ----------------
__global__ __launch_bounds__(256) void k_stats(const float* __restrict__ x,
        const float* __restrict__ temb, const float* __restrict__ gamma,
        const float* __restrict__ beta, float* __restrict__ aArr,
        float* __restrict__ offArr) {
    int c = blockIdx.x, t = threadIdx.x;
    __shared__ float wred[4];
    __shared__ float snA[NBb];
    float sq = 0.f;
    for (int n = 0; n < NBb; n++) {
        const float4 v = reinterpret_cast<const float4*>(x + (size_t)(n*D_INc + c)*Sc)[t];
        float s = v.x + v.y + v.z + v.w;
        sq += v.x*v.x + v.y*v.y + v.z*v.z + v.w*v.w;
        for (int msk = 32; msk >= 1; msk >>= 1) s += __shfl_xor(s, msk);
        if ((t & 63) == 0) wred[t >> 6] = s;
        __syncthreads();
        if (t == 0) snA[n] = wred[0] + wred[1] + wred[2] + wred[3];
        __syncthreads();
    }
    for (int msk = 32; msk >= 1; msk >>= 1) sq += __shfl_xor(sq, msk);
    if ((t & 63) == 0) wred[t >> 6] = sq;
    __syncthreads();
    if (t == 0) {
        float sumsq = wred[0]+wred[1]+wred[2]+wred[3];
        float sumx = 0.f, tsum = 0.f, tsq = 0.f, cross = 0.f;
        for (int n = 0; n < NBb; n++) {
            float tv = temb[n*D_INc + c];
            sumx += snA[n]; tsum += tv; tsq += tv*tv; cross += tv*snA[n];
        }
        const float inv = 1.f / (float)(NBb * Sc);
        float mean = (sumx + (float)Sc * tsum) * inv;
        float ex2  = (sumsq + 2.f*cross + (float)Sc * tsq) * inv;
        float var  = ex2 - mean*mean;
        float a = gamma[c] * rsqrtf(var + EPSV);
        aArr[c] = a;
        float b = beta[c];
        for (int n = 0; n < NBb; n++)
            offArr[n*D_INc + c] = (temb[n*D_INc + c] - mean) * a + b;
    }
}

// ---------------- K3: weight prep to bf16 (same indexing as verified f32 version) ----------------
__global__ __launch_bounds__(256) void k_prepwb(const float* __restrict__ Wq,
        const float* __restrict__ Wk, const float* __restrict__ Wv,
        const float* __restrict__ Wp,
        __hip_bfloat16* __restrict__ wqkvb, __hip_bfloat16* __restrict__ wptb) {
    int b = blockIdx.x, t = threadIdx.x;
    if (b < 1088) {
        float v;
        if (b < 512) v = Wq[t*D_KQc + b];
        else if (b < 1024) v = Wk[t*D_KQc + (b-512)];
        else v = Wv[t*D_Vc + (b-1024)];
        wqkvb[b*D_INc + t] = __float2bfloat16(v);
    } else {
        int cout = b - 1088;
        for (int j = t; j < 512; j += 256) {
            int r = (j & 63)*8 + (j >> 6);
            wptb[cout*512 + j] = __float2bfloat16(Wp[r*D_INc + cout]);
        }
    }
}

// ---------------- K4: xsb[n][s][c] = x[n][c][s]*a[c] + off[n][c]  (bf16, scalar stores) ----------------
__global__ __launch_bounds__(256) void k_xsb(const float* __restrict__ x,
        const float* __restrict__ aArr, const float* __restrict__ offArr,
        __hip_bfloat16* __restrict__ xsb) {
    __shared__ float tile[64][65];
    int s0 = blockIdx.x * 64, c0 = blockIdx.y * 64, n = blockIdx.z;
    int t = threadIdx.x;
    #pragma unroll
    for (int p = 0; p < 16; p++) {
        int idx = p*256 + t;
        int cl = idx >> 6, sl = idx & 63;
        int c = c0 + cl;
        tile[cl][sl] = x[((size_t)(n*D_INc + c))*Sc + s0 + sl] * aArr[c] + offArr[n*D_INc + c];
    }
    __syncthreads();
    #pragma unroll
    for (int p = 0; p < 16; p++) {
        int idx = p*256 + t;
        int sl = idx >> 6, cl = idx & 63;
        xsb[((size_t)(n*Sc + s0 + sl))*D_INc + c0 + cl] = __float2bfloat16(tile[cl][sl]);
    }
}

// ---------------- K5: QKV bf16 MFMA. C[s][j] = xsb[s][:].wqkvb[j][:] ----------------
// j<512 -> qbv (pre-scaled by 1/sqrt(512)*log2e); 512..1023 -> kbv; 1024.. -> vbv[dv][s]
__global__ __launch_bounds__(256) void k_qkvb(const __hip_bfloat16* __restrict__ xsb,
        const __hip_bfloat16* __restrict__ wqkvb, __hip_bfloat16* __restrict__ qbv,
        __hip_bfloat16* __restrict__ kbv, __hip_bfloat16* __restrict__ vbv) {
    int jt = blockIdx.x, st = blockIdx.y, n = blockIdx.z;
    int t = threadIdx.x, w = t >> 6, l = t & 63;
    int lr = l & 15, lg = l >> 4;
    int s0 = st*64, j0 = jt*64;
    const bf16x8* A = reinterpret_cast<const bf16x8*>(xsb + ((size_t)(n*Sc + s0 + w*16 + lr))*D_INc + lg*8);
    const bf16x8* B = reinterpret_cast<const bf16x8*>(wqkvb + ((size_t)(j0 + lr))*D_INc + lg*8);
    f32x4 acc[4] = {};
    for (int kk = 0; kk < 8; kk++) {
        bf16x8 a = A[kk*4];
        #pragma unroll
        for (int nt = 0; nt < 4; nt++) {
            bf16x8 b = B[nt*512 + kk*4];
            acc[nt] = __builtin_amdgcn_mfma_f32_16x16x32_bf16(a, b, acc[nt], 0, 0, 0);
        }
    }
    const float QSC = 0.044194173824159216f * 1.4426950408889634f; // scale * log2(e)
    if (j0 < 512) {
        #pragma unroll
        for (int nt = 0; nt < 4; nt++)
            #pragma unroll
            for (int r = 0; r < 4; r++)
                qbv[((size_t)(n*Sc + s0 + w*16 + lg*4 + r))*512 + j0 + nt*16 + lr] =
                    __float2bfloat16(acc[nt][r] * QSC);
    } else if (j0 < 1024) {
        #pragma unroll
        for (int nt = 0; nt < 4; nt++)
            #pragma unroll
            for (int r = 0; r < 4; r++)
                kbv[((size_t)(n*Sc + s0 + w*16 + lg*4 + r))*512 + (j0 - 512) + nt*16 + lr] =
                    __float2bfloat16(acc[nt][r]);
    } else {
        #pragma unroll
        for (int nt = 0; nt < 4; nt++)
            #pragma unroll
            for (int r = 0; r < 4; r++)
                vbv[((size_t)(n*D_Vc + nt*16 + lr))*Sc + s0 + w*16 + lg*4 + r] =
                    __float2bfloat16(acc[nt][r]);
    }
}

// ---------------- K6: MFMA attention, barrier-free loop, KVBLK=64, defer-max ----------------
// Scores are in log2 domain (Q pre-scaled). S^T = mfma(K,Q); lane(lr,lg) holds
// S[q=lr][key = k0+16g+lg*4+r]. P redistributed via shfl (verified ≡ LDS staging).
__global__ __launch_bounds__(256) void k_attnb(const __hip_bfloat16* __restrict__ qbv,
        const __hip_bfloat16* __restrict__ kbv, const __hip_bfloat16* __restrict__ vbv,
        __hip_bfloat16* __restrict__ obb) {
    __shared__ float olds[4][16][68];
    int qt = blockIdx.x, h = blockIdx.y, n = blockIdx.z;
    int t = threadIdx.x, w = t >> 6, l = t & 63;
    int lr = l & 15, lg = l >> 4;
    int q0 = qt*64 + w*16;
    const __hip_bfloat16* qrow = qbv + ((size_t)(n*Sc + q0 + lr))*512 + h*64 + lg*8;
    bf16x8 qf0 = *reinterpret_cast<const bf16x8*>(qrow);
    bf16x8 qf1 = *reinterpret_cast<const bf16x8*>(qrow + 32);
    const __hip_bfloat16* kbase = kbv + (size_t)n*Sc*512 + h*64 + lg*8;
    const __hip_bfloat16* vbase = vbv + (size_t)n*D_Vc*Sc + lg*8;
    float m = -1e30f, lsum = 0.f;
    f32x4 oacc[4] = {};
    for (int kc = 0; kc < 16; kc++) {
        int k0 = kc*64;
        f32x4 sa[4] = {};
        #pragma unroll
        for (int g = 0; g < 4; g++) {
            const __hip_bfloat16* kr = kbase + (size_t)(k0 + g*16 + lr)*512;
            bf16x8 klo = *reinterpret_cast<const bf16x8*>(kr);
            bf16x8 khi = *reinterpret_cast<const bf16x8*>(kr + 32);
            sa[g] = __builtin_amdgcn_mfma_f32_16x16x32_bf16(klo, qf0, sa[g], 0,0,0);
            sa[g] = __builtin_amdgcn_mfma_f32_16x16x32_bf16(khi, qf1, sa[g], 0,0,0);
        }
        float sv[16];
        #pragma unroll
        for (int g = 0; g < 4; g++)
            #pragma unroll
            for (int r = 0; r < 4; r++) sv[g*4 + r] = sa[g][r];
        float cmax = sv[0];
        #pragma unroll
        for (int i = 1; i < 16; i++) cmax = fmaxf(cmax, sv[i]);
        if (!__all(cmax <= m + 11.0f)) {   // defer-max: rescale only on real growth
            cmax = fmaxf(cmax, __shfl_xor(cmax, 16));
            cmax = fmaxf(cmax, __shfl_xor(cmax, 32));
            float mnew = fmaxf(m, cmax);
            float sf = exp2f(m - mnew);
            lsum *= sf;
            #pragma unroll
            for (int mt = 0; mt < 4; mt++)
                #pragma unroll
                for (int r = 0; r < 4; r++) oacc[mt][r] *= sf;
            m = mnew;
        }
        float p[16];
        #pragma unroll
        for (int i = 0; i < 16; i++) { p[i] = exp2f(sv[i] - m); lsum += p[i]; }
        int srcA = lr + ((l & 16) ? 32 : 0);
        int srcB = srcA + 16;
        bool hi = (l & 32) != 0;
        #pragma unroll
        for (int half = 0; half < 2; half++) {
            unsigned int u00 = pack2(p[half*8+0], p[half*8+1]);
            unsigned int u01 = pack2(p[half*8+2], p[half*8+3]);
            unsigned int u10 = pack2(p[half*8+4], p[half*8+5]);
            unsigned int u11 = pack2(p[half*8+6], p[half*8+7]);
            unsigned int a0 = (unsigned int)__shfl((int)u00, srcA);
            unsigned int h0 = (unsigned int)__shfl((int)u10, srcA);
            unsigned int a1 = (unsigned int)__shfl((int)u01, srcA);
            unsigned int h1 = (unsigned int)__shfl((int)u11, srcA);
            unsigned int a2 = (unsigned int)__shfl((int)u00, srcB);
            unsigned int h2 = (unsigned int)__shfl((int)u10, srcB);
            unsigned int a3 = (unsigned int)__shfl((int)u01, srcB);
            unsigned int h3 = (unsigned int)__shfl((int)u11, srcB);
            uint4 pvu = { hi?h0:a0, hi?h1:a1, hi?h2:a2, hi?h3:a3 };
            bf16x8 pb = __builtin_bit_cast(bf16x8, pvu);
            int kch = k0 + half*32;
            #pragma unroll
            for (int mt = 0; mt < 4; mt++) {
                bf16x8 vf = *reinterpret_cast<const bf16x8*>(vbase + (size_t)(mt*16 + lr)*Sc + kch);
                oacc[mt] = __builtin_amdgcn_mfma_f32_16x16x32_bf16(vf, pb, oacc[mt], 0,0,0);
            }
        }
    }
    lsum += __shfl_xor(lsum, 16);
    lsum += __shfl_xor(lsum, 32);
    float inv = 1.f / lsum;
    #pragma unroll
    for (int mt = 0; mt < 4; mt++)
        #pragma unroll
        for (int r = 0; r < 4; r++)
            olds[w][lr][mt*16 + lg*4 + r] = oacc[mt][r] * inv;
    __syncthreads();
    int ql = l >> 2, dvb = (l & 3) * 16;
    unsigned int* op = reinterpret_cast<unsigned int*>(
        obb + ((size_t)(n*Sc + qt*64 + w*16 + ql))*512 + h*64 + dvb);
    #pragma unroll
    for (int i = 0; i < 8; i++)
        op[i] = pack2(olds[w][ql][dvb + 2*i], olds[w][ql][dvb + 2*i + 1]);
}

// ---------------- K7: bf16 MFMA proj. out[n][c][s] = obb[s][:].wptb[c][:] + bp[c] + x ----------------
__global__ __launch_bounds__(256) void k_projb(const __hip_bfloat16* __restrict__ obb,
        const __hip_bfloat16* __restrict__ wptb, const float* __restrict__ bp,
        const float* __restrict__ x, float* __restrict__ out) {
    int st = blockIdx.x, ct = blockIdx.y, n = blockIdx.z;
    int t = threadIdx.x, w = t >> 6, l = t & 63;
    int lr = l & 15, lg = l >> 4;
    int s0 = st*64, c0 = ct*64 + w*16;
    const bf16x8* A = reinterpret_cast<const bf16x8*>(wptb + ((size_t)(c0 + lr))*512 + lg*8);
    const bf16x8* B = reinterpret_cast<const bf16x8*>(obb + ((size_t)(n*Sc + s0 + lr))*512 + lg*8);
    f32x4 acc[4] = {};
    for (int kk = 0; kk < 16; kk++) {
        bf16x8 a = A[kk*4];
        #pragma unroll
        for (int nt = 0; nt < 4; nt++) {
            bf16x8 b = B[nt*1024 + kk*4];
            acc[nt] = __builtin_amdgcn_mfma_f32_16x16x32_bf16(a, b, acc[nt], 0,0,0);
        }
    }
    #pragma unroll
    for (int nt = 0; nt < 4; nt++) {
        #pragma unroll
        for (int r = 0; r < 4; r++) {
            int c = c0 + lg*4 + r;
            size_t idx = ((size_t)(n*D_INc + c))*Sc + s0 + nt*16 + lr;
            out[idx] = acc[nt][r] + bp[c] + x[idx];
        }
    }
}

extern "C" void kernel_launch(void* const* d_in, const int* in_sizes, int n_in,
                              void* d_out, int out_size, void* d_ws, size_t ws_size,
                              hipStream_t stream) {
    const float* x     = (const float*)d_in[0];
    const float* t     = (const float*)d_in[1];
    const float* Wt    = (const float*)d_in[2];
    const float* bt    = (const float*)d_in[3];
    const float* Wq    = (const float*)d_in[4];
    const float* Wk    = (const float*)d_in[5];
    const float* Wv    = (const float*)d_in[6];
    const float* Wp    = (const float*)d_in[7];
    const float* bp    = (const float*)d_in[8];
    const float* gamma = (const float*)d_in[9];
    const float* beta  = (const float*)d_in[10];
    char* ws = (char*)d_ws;
    float* temb  = (float*)(ws + 0);               // 8 KB
    float* aArr  = (float*)(ws + 8192);            // 1 KB
    float* offA  = (float*)(ws + 9216);            // 8 KB
    __hip_bfloat16* wqkvb = (__hip_bfloat16*)(ws + 32768);     // 544 KB [1088][256]
    __hip_bfloat16* wptb  = (__hip_bfloat16*)(ws + 589824);    // 256 KB [256][512]
    __hip_bfloat16* xsb   = (__hip_bfloat16*)(ws + 1048576);   // 4 MB [8][1024][256]
    __hip_bfloat16* qbv   = (__hip_bfloat16*)(ws + 5242880);   // 8 MB [8][1024][512]
    __hip_bfloat16* kbv   = (__hip_bfloat16*)(ws + 13631488);  // 8 MB [8][1024][512]
    __hip_bfloat16* vbv   = (__hip_bfloat16*)(ws + 22020096);  // 1 MB [8][64][1024]
    __hip_bfloat16* obb   = (__hip_bfloat16*)(ws + 23068672);  // 8 MB [8][1024][512]
    float* out = (float*)d_out;

    hipLaunchKernelGGL(k_temb,   dim3(8),        dim3(256), 0, stream, t, Wt, bt, temb);
    hipLaunchKernelGGL(k_stats,  dim3(256),      dim3(256), 0, stream, x, temb, gamma, beta, aArr, offA);
    hipLaunchKernelGGL(k_prepwb, dim3(1344),     dim3(256), 0, stream, Wq, Wk, Wv, Wp, wqkvb, wptb);
    hipLaunchKernelGGL(k_xsb,    dim3(16,4,8),   dim3(256), 0, stream, x, aArr, offA, xsb);
    hipLaunchKernelGGL(k_qkvb,   dim3(17,16,8),  dim3(256), 0, stream, xsb, wqkvb, qbv, kbv, vbv);
    hipLaunchKernelGGL(k_attnb,  dim3(16,8,8),   dim3(256), 0, stream, qbv, kbv, vbv, obb);
    hipLaunchKernelGGL(k_projb,  dim3(16,4,8),   dim3(256), 0, stream, obb, wptb, bp, x, out);
}

// Round 7
// 150.708 us; speedup vs baseline: 14.3354x; 1.4865x over previous
//
#include <hip/hip_runtime.h>
#include <hip/hip_bf16.h>

#define D_INc 256
#define D_KQc 512
#define D_Vc 64
#define NBb 8
#define Sc 1024
#define TDIMc 512
#define EPSV 1e-5f

typedef __bf16 bf16x8 __attribute__((ext_vector_type(8)));
typedef float f32x4 __attribute__((ext_vector_type(4)));

__device__ inline unsigned short f2bf(float f) {
    return __builtin_bit_cast(unsigned short, __float2bfloat16(f));
}
__device__ inline unsigned int pack2(float a, float b) {
    return (unsigned int)f2bf(a) | ((unsigned int)f2bf(b) << 16);
}

// ---------------- K1: temb = relu(t @ Wt + bt)  [8,256]  (verified) ----------------
__global__ __launch_bounds__(256) void k_temb(const float* __restrict__ t,
        const float* __restrict__ Wt, const float* __restrict__ bt,
        float* __restrict__ temb) {
    __shared__ float tl[TDIMc];
    int n = blockIdx.x, c = threadIdx.x;
    tl[c] = t[n*TDIMc + c];
    tl[c+256] = t[n*TDIMc + c + 256];
    __syncthreads();
    float acc = bt[c];
    #pragma unroll 8
    for (int i = 0; i < TDIMc; i++) acc += tl[i] * Wt[i*D_INc + c];
    temb[n*D_INc + c] = fmaxf(acc, 0.f);
}

// ---------------- K2: BN stats -> a[c], off[n][c]  (verified) ----------------
__global__ __launch_bounds__(256) void k_stats(const float* __restrict__ x,
        const float* __restrict__ temb, const float* __restrict__ gamma,
        const float* __restrict__ beta, float* __restrict__ aArr,
        float* __restrict__ offArr) {
    int c = blockIdx.x, t = threadIdx.x;
    __shared__ float wred[4];
    __shared__ float snA[NBb];
    float sq = 0.f;
    for (int n = 0; n < NBb; n++) {
        const float4 v = reinterpret_cast<const float4*>(x + (size_t)(n*D_INc + c)*Sc)[t];
        float s = v.x + v.y + v.z + v.w;
        sq += v.x*v.x + v.y*v.y + v.z*v.z + v.w*v.w;
        for (int msk = 32; msk >= 1; msk >>= 1) s += __shfl_xor(s, msk);
        if ((t & 63) == 0) wred[t >> 6] = s;
        __syncthreads();
        if (t == 0) snA[n] = wred[0] + wred[1] + wred[2] + wred[3];
        __syncthreads();
    }
    for (int msk = 32; msk >= 1; msk >>= 1) sq += __shfl_xor(sq, msk);
    if ((t & 63) == 0) wred[t >> 6] = sq;
    __syncthreads();
    if (t == 0) {
        float sumsq = wred[0]+wred[1]+wred[2]+wred[3];
        float sumx = 0.f, tsum = 0.f, tsq = 0.f, cross = 0.f;
        for (int n = 0; n < NBb; n++) {
            float tv = temb[n*D_INc + c];
            sumx += snA[n]; tsum += tv; tsq += tv*tv; cross += tv*snA[n];
        }
        const float inv = 1.f / (float)(NBb * Sc);
        float mean = (sumx + (float)Sc * tsum) * inv;
        float ex2  = (sumsq + 2.f*cross + (float)Sc * tsq) * inv;
        float var  = ex2 - mean*mean;
        float a = gamma[c] * rsqrtf(var + EPSV);
        aArr[c] = a;
        float b = beta[c];
        for (int n = 0; n < NBb; n++)
            offArr[n*D_INc + c] = (temb[n*D_INc + c] - mean) * a + b;
    }
}

// ---------------- K3: weight prep to bf16 (verified indexing) ----------------
__global__ __launch_bounds__(256) void k_prepwb(const float* __restrict__ Wq,
        const float* __restrict__ Wk, const float* __restrict__ Wv,
        const float* __restrict__ Wp,
        __hip_bfloat16* __restrict__ wqkvb, __hip_bfloat16* __restrict__ wptb) {
    int b = blockIdx.x, t = threadIdx.x;
    if (b < 1088) {
        float v;
        if (b < 512) v = Wq[t*D_KQc + b];
        else if (b < 1024) v = Wk[t*D_KQc + (b-512)];
        else v = Wv[t*D_Vc + (b-1024)];
        wqkvb[b*D_INc + t] = __float2bfloat16(v);
    } else {
        int cout = b - 1088;
        for (int j = t; j < 512; j += 256) {
            int r = (j & 63)*8 + (j >> 6);
            wptb[cout*512 + j] = __float2bfloat16(Wp[r*D_INc + cout]);
        }
    }
}

// ---------------- K4: xsb[n][s][c] = x[n][c][s]*a[c] + off[n][c]  (bf16) ----------------
__global__ __launch_bounds__(256) void k_xsb(const float* __restrict__ x,
        const float* __restrict__ aArr, const float* __restrict__ offArr,
        __hip_bfloat16* __restrict__ xsb) {
    __shared__ float tile[64][65];
    int s0 = blockIdx.x * 64, c0 = blockIdx.y * 64, n = blockIdx.z;
    int t = threadIdx.x;
    #pragma unroll
    for (int p = 0; p < 16; p++) {
        int idx = p*256 + t;
        int cl = idx >> 6, sl = idx & 63;
        int c = c0 + cl;
        tile[cl][sl] = x[((size_t)(n*D_INc + c))*Sc + s0 + sl] * aArr[c] + offArr[n*D_INc + c];
    }
    __syncthreads();
    #pragma unroll
    for (int p = 0; p < 16; p++) {
        int idx = p*256 + t;
        int sl = idx >> 6, cl = idx & 63;
        xsb[((size_t)(n*Sc + s0 + sl))*D_INc + c0 + cl] = __float2bfloat16(tile[cl][sl]);
    }
}

// ---------------- K5: QKV bf16 MFMA -> fragment-ordered Q/K/V ----------------
// qfrag[((n*8+h)*64 + (s>>4))*2 + dhalf][lane][8]  lane=(s&15)+16*((d&31)>>3), elem d&7
// kfrag: same shape (keys).  vfrag[(n*32 + (s>>5))*4 + (dv>>4)][lane][8]
//        lane=(dv&15)+16*((s&31)>>3), elem s&7.   Q pre-scaled by scale*log2e.
__global__ __launch_bounds__(256) void k_qkvb(const __hip_bfloat16* __restrict__ xsb,
        const __hip_bfloat16* __restrict__ wqkvb, __hip_bfloat16* __restrict__ qfrag,
        __hip_bfloat16* __restrict__ kfrag, __hip_bfloat16* __restrict__ vfrag) {
    int jt = blockIdx.x, st = blockIdx.y, n = blockIdx.z;
    int t = threadIdx.x, w = t >> 6, l = t & 63;
    int lr = l & 15, lg = l >> 4;
    int s0 = st*64, j0 = jt*64;
    const bf16x8* A = reinterpret_cast<const bf16x8*>(xsb + ((size_t)(n*Sc + s0 + w*16 + lr))*D_INc + lg*8);
    const bf16x8* B = reinterpret_cast<const bf16x8*>(wqkvb + ((size_t)(j0 + lr))*D_INc + lg*8);
    f32x4 acc[4] = {};
    for (int kk = 0; kk < 8; kk++) {
        bf16x8 a = A[kk*4];
        #pragma unroll
        for (int nt = 0; nt < 4; nt++) {
            bf16x8 b = B[nt*512 + kk*4];
            acc[nt] = __builtin_amdgcn_mfma_f32_16x16x32_bf16(a, b, acc[nt], 0, 0, 0);
        }
    }
    const float QSC = 0.044194173824159216f * 1.4426950408889634f; // scale * log2(e)
    #pragma unroll
    for (int nt = 0; nt < 4; nt++) {
        #pragma unroll
        for (int r = 0; r < 4; r++) {
            int s = s0 + w*16 + lg*4 + r;          // token index
            int j = j0 + nt*16 + lr;               // output-feature index
            float v = acc[nt][r];
            if (j0 < 512) {
                int h = j >> 6, d = j & 63;
                size_t idx = ((((size_t)(n*8 + h)*64 + (s>>4))*2 + (d>>5))*64
                              + ((s&15) + 16*((d&31)>>3)))*8 + (d&7);
                qfrag[idx] = __float2bfloat16(v * QSC);
            } else if (j0 < 1024) {
                int jk = j - 512;
                int h = jk >> 6, d = jk & 63;
                size_t idx = ((((size_t)(n*8 + h)*64 + (s>>4))*2 + (d>>5))*64
                              + ((s&15) + 16*((d&31)>>3)))*8 + (d&7);
                kfrag[idx] = __float2bfloat16(v);
            } else {
                int dv = j - 1024;
                size_t idx = (((size_t)(n*32 + (s>>5))*4 + (dv>>4))*64
                              + ((dv&15) + 16*((s&31)>>3)))*8 + (s&7);
                vfrag[idx] = __float2bfloat16(v);
            }
        }
    }
}

// ---------------- K6: MFMA attention; all loads coalesced via frag layout ----------------
__global__ __launch_bounds__(256) void k_attnb(const __hip_bfloat16* __restrict__ qfrag,
        const __hip_bfloat16* __restrict__ kfrag, const __hip_bfloat16* __restrict__ vfrag,
        __hip_bfloat16* __restrict__ obb) {
    __shared__ float olds[4][16][68];
    int qt = blockIdx.x, h = blockIdx.y, n = blockIdx.z;
    int t = threadIdx.x, w = t >> 6, l = t & 63;
    int lr = l & 15, lg = l >> 4;
    int qb2 = qt*4 + w;                    // 16-q block index 0..63
    const __hip_bfloat16* qbase = qfrag + (((size_t)(n*8 + h)*64 + qb2)*2)*512 + l*8;
    bf16x8 qf0 = *reinterpret_cast<const bf16x8*>(qbase);
    bf16x8 qf1 = *reinterpret_cast<const bf16x8*>(qbase + 512);
    const __hip_bfloat16* kf = kfrag + ((size_t)(n*8 + h)*64)*1024 + l*8;  // per kb16: 1024 elems
    const __hip_bfloat16* vf = vfrag + (size_t)n*32*2048 + l*8;            // per kb32: 2048 elems
    float m = -1e30f, lsum = 0.f;
    f32x4 oacc[4] = {};
    for (int kc = 0; kc < 16; kc++) {
        f32x4 sa[4] = {};
        #pragma unroll
        for (int g = 0; g < 4; g++) {
            const __hip_bfloat16* kr = kf + (size_t)(kc*4 + g)*1024;
            bf16x8 klo = *reinterpret_cast<const bf16x8*>(kr);
            bf16x8 khi = *reinterpret_cast<const bf16x8*>(kr + 512);
            sa[g] = __builtin_amdgcn_mfma_f32_16x16x32_bf16(klo, qf0, sa[g], 0,0,0);
            sa[g] = __builtin_amdgcn_mfma_f32_16x16x32_bf16(khi, qf1, sa[g], 0,0,0);
        }
        float sv[16];
        #pragma unroll
        for (int g = 0; g < 4; g++)
            #pragma unroll
            for (int r = 0; r < 4; r++) sv[g*4 + r] = sa[g][r];
        float cmax = sv[0];
        #pragma unroll
        for (int i = 1; i < 16; i++) cmax = fmaxf(cmax, sv[i]);
        if (!__all(cmax <= m + 11.0f)) {   // defer-max
            cmax = fmaxf(cmax, __shfl_xor(cmax, 16));
            cmax = fmaxf(cmax, __shfl_xor(cmax, 32));
            float mnew = fmaxf(m, cmax);
            float sf = exp2f(m - mnew);
            lsum *= sf;
            #pragma unroll
            for (int mt = 0; mt < 4; mt++)
                #pragma unroll
                for (int r = 0; r < 4; r++) oacc[mt][r] *= sf;
            m = mnew;
        }
        float p[16];
        #pragma unroll
        for (int i = 0; i < 16; i++) { p[i] = exp2f(sv[i] - m); lsum += p[i]; }
        int srcA = lr + ((l & 16) ? 32 : 0);
        int srcB = srcA + 16;
        bool hi = (l & 32) != 0;
        #pragma unroll
        for (int half = 0; half < 2; half++) {
            unsigned int u00 = pack2(p[half*8+0], p[half*8+1]);
            unsigned int u01 = pack2(p[half*8+2], p[half*8+3]);
            unsigned int u10 = pack2(p[half*8+4], p[half*8+5]);
            unsigned int u11 = pack2(p[half*8+6], p[half*8+7]);
            unsigned int a0 = (unsigned int)__shfl((int)u00, srcA);
            unsigned int h0 = (unsigned int)__shfl((int)u10, srcA);
            unsigned int a1 = (unsigned int)__shfl((int)u01, srcA);
            unsigned int h1 = (unsigned int)__shfl((int)u11, srcA);
            unsigned int a2 = (unsigned int)__shfl((int)u00, srcB);
            unsigned int h2 = (unsigned int)__shfl((int)u10, srcB);
            unsigned int a3 = (unsigned int)__shfl((int)u01, srcB);
            unsigned int h3 = (unsigned int)__shfl((int)u11, srcB);
            uint4 pvu = { hi?h0:a0, hi?h1:a1, hi?h2:a2, hi?h3:a3 };
            bf16x8 pb = __builtin_bit_cast(bf16x8, pvu);
            const __hip_bfloat16* vblk = vf + (size_t)(kc*2 + half)*2048;
            #pragma unroll
            for (int mt = 0; mt < 4; mt++) {
                bf16x8 vfr = *reinterpret_cast<const bf16x8*>(vblk + mt*512);
                oacc[mt] = __builtin_amdgcn_mfma_f32_16x16x32_bf16(vfr, pb, oacc[mt], 0,0,0);
            }
        }
    }
    lsum += __shfl_xor(lsum, 16);
    lsum += __shfl_xor(lsum, 32);
    float inv = 1.f / lsum;
    #pragma unroll
    for (int mt = 0; mt < 4; mt++)
        #pragma unroll
        for (int r = 0; r < 4; r++)
            olds[w][lr][mt*16 + lg*4 + r] = oacc[mt][r] * inv;
    __syncthreads();
    int ql = l >> 2, dvb = (l & 3) * 16;
    unsigned int* op = reinterpret_cast<unsigned int*>(
        obb + ((size_t)(n*Sc + qb2*16 + ql))*512 + h*64 + dvb);
    #pragma unroll
    for (int i = 0; i < 8; i++)
        op[i] = pack2(olds[w][ql][dvb + 2*i], olds[w][ql][dvb + 2*i + 1]);
}

// ---------------- K7: bf16 MFMA proj. out[n][c][s] = obb[s][:].wptb[c][:] + bp[c] + x ----------------
__global__ __launch_bounds__(256) void k_projb(const __hip_bfloat16* __restrict__ obb,
        const __hip_bfloat16* __restrict__ wptb, const float* __restrict__ bp,
        const float* __restrict__ x, float* __restrict__ out) {
    int st = blockIdx.x, ct = blockIdx.y, n = blockIdx.z;
    int t = threadIdx.x, w = t >> 6, l = t & 63;
    int lr = l & 15, lg = l >> 4;
    int s0 = st*64, c0 = ct*64 + w*16;
    const bf16x8* A = reinterpret_cast<const bf16x8*>(wptb + ((size_t)(c0 + lr))*512 + lg*8);
    const bf16x8* B = reinterpret_cast<const bf16x8*>(obb + ((size_t)(n*Sc + s0 + lr))*512 + lg*8);
    f32x4 acc[4] = {};
    for (int kk = 0; kk < 16; kk++) {
        bf16x8 a = A[kk*4];
        #pragma unroll
        for (int nt = 0; nt < 4; nt++) {
            bf16x8 b = B[nt*1024 + kk*4];
            acc[nt] = __builtin_amdgcn_mfma_f32_16x16x32_bf16(a, b, acc[nt], 0,0,0);
        }
    }
    #pragma unroll
    for (int nt = 0; nt < 4; nt++) {
        #pragma unroll
        for (int r = 0; r < 4; r++) {
            int c = c0 + lg*4 + r;
            size_t idx = ((size_t)(n*D_INc + c))*Sc + s0 + nt*16 + lr;
            out[idx] = acc[nt][r] + bp[c] + x[idx];
        }
    }
}

extern "C" void kernel_launch(void* const* d_in, const int* in_sizes, int n_in,
                              void* d_out, int out_size, void* d_ws, size_t ws_size,
                              hipStream_t stream) {
    const float* x     = (const float*)d_in[0];
    const float* t     = (const float*)d_in[1];
    const float* Wt    = (const float*)d_in[2];
    const float* bt    = (const float*)d_in[3];
    const float* Wq    = (const float*)d_in[4];
    const float* Wk    = (const float*)d_in[5];
    const float* Wv    = (const float*)d_in[6];
    const float* Wp    = (const float*)d_in[7];
    const float* bp    = (const float*)d_in[8];
    const float* gamma = (const float*)d_in[9];
    const float* beta  = (const float*)d_in[10];
    char* ws = (char*)d_ws;
    float* temb  = (float*)(ws + 0);               // 8 KB
    float* aArr  = (float*)(ws + 8192);            // 1 KB
    float* offA  = (float*)(ws + 9216);            // 8 KB
    __hip_bfloat16* wqkvb = (__hip_bfloat16*)(ws + 32768);     // 544 KB [1088][256]
    __hip_bfloat16* wptb  = (__hip_bfloat16*)(ws + 589824);    // 256 KB [256][512]
    __hip_bfloat16* xsb   = (__hip_bfloat16*)(ws + 1048576);   // 4 MB [8][1024][256]
    __hip_bfloat16* qfrag = (__hip_bfloat16*)(ws + 5242880);   // 8 MB
    __hip_bfloat16* kfrag = (__hip_bfloat16*)(ws + 13631488);  // 8 MB
    __hip_bfloat16* vfrag = (__hip_bfloat16*)(ws + 22020096);  // 1 MB
    __hip_bfloat16* obb   = (__hip_bfloat16*)(ws + 23068672);  // 8 MB [8][1024][512]
    float* out = (float*)d_out;

    hipLaunchKernelGGL(k_temb,   dim3(8),        dim3(256), 0, stream, t, Wt, bt, temb);
    hipLaunchKernelGGL(k_stats,  dim3(256),      dim3(256), 0, stream, x, temb, gamma, beta, aArr, offA);
    hipLaunchKernelGGL(k_prepwb, dim3(1344),     dim3(256), 0, stream, Wq, Wk, Wv, Wp, wqkvb, wptb);
    hipLaunchKernelGGL(k_xsb,    dim3(16,4,8),   dim3(256), 0, stream, x, aArr, offA, xsb);
    hipLaunchKernelGGL(k_qkvb,   dim3(17,16,8),  dim3(256), 0, stream, xsb, wqkvb, qfrag, kfrag, vfrag);
    hipLaunchKernelGGL(k_attnb,  dim3(16,8,8),   dim3(256), 0, stream, qfrag, kfrag, vfrag, obb);
    hipLaunchKernelGGL(k_projb,  dim3(16,4,8),   dim3(256), 0, stream, obb, wptb, bp, x, out);
}

// Round 8
// 112.491 us; speedup vs baseline: 19.2055x; 1.3397x over previous
//
#include <hip/hip_runtime.h>
#include <hip/hip_bf16.h>

#define D_INc 256
#define D_KQc 512
#define D_Vc 64
#define NBb 8
#define Sc 1024
#define TDIMc 512
#define EPSV 1e-5f

typedef __bf16 bf16x8 __attribute__((ext_vector_type(8)));
typedef float f32x4 __attribute__((ext_vector_type(4)));

__device__ inline unsigned short f2bf(float f) {
    return __builtin_bit_cast(unsigned short, __float2bfloat16(f));
}
__device__ inline unsigned int pack2(float a, float b) {
    return (unsigned int)f2bf(a) | ((unsigned int)f2bf(b) << 16);
}

// ---------------- K1: temb = relu(t @ Wt + bt)  [8,256]  (verified) ----------------
__global__ __launch_bounds__(256) void k_temb(const float* __restrict__ t,
        const float* __restrict__ Wt, const float* __restrict__ bt,
        float* __restrict__ temb) {
    __shared__ float tl[TDIMc];
    int n = blockIdx.x, c = threadIdx.x;
    tl[c] = t[n*TDIMc + c];
    tl[c+256] = t[n*TDIMc + c + 256];
    __syncthreads();
    float acc = bt[c];
    #pragma unroll 8
    for (int i = 0; i < TDIMc; i++) acc += tl[i] * Wt[i*D_INc + c];
    temb[n*D_INc + c] = fmaxf(acc, 0.f);
}

// ---------------- K2: BN stats -> a[c], off[n][c]  (verified) ----------------
__global__ __launch_bounds__(256) void k_stats(const float* __restrict__ x,
        const float* __restrict__ temb, const float* __restrict__ gamma,
        const float* __restrict__ beta, float* __restrict__ aArr,
        float* __restrict__ offArr) {
    int c = blockIdx.x, t = threadIdx.x;
    __shared__ float wred[4];
    __shared__ float snA[NBb];
    float sq = 0.f;
    for (int n = 0; n < NBb; n++) {
        const float4 v = reinterpret_cast<const float4*>(x + (size_t)(n*D_INc + c)*Sc)[t];
        float s = v.x + v.y + v.z + v.w;
        sq += v.x*v.x + v.y*v.y + v.z*v.z + v.w*v.w;
        for (int msk = 32; msk >= 1; msk >>= 1) s += __shfl_xor(s, msk);
        if ((t & 63) == 0) wred[t >> 6] = s;
        __syncthreads();
        if (t == 0) snA[n] = wred[0] + wred[1] + wred[2] + wred[3];
        __syncthreads();
    }
    for (int msk = 32; msk >= 1; msk >>= 1) sq += __shfl_xor(sq, msk);
    if ((t & 63) == 0) wred[t >> 6] = sq;
    __syncthreads();
    if (t == 0) {
        float sumsq = wred[0]+wred[1]+wred[2]+wred[3];
        float sumx = 0.f, tsum = 0.f, tsq = 0.f, cross = 0.f;
        for (int n = 0; n < NBb; n++) {
            float tv = temb[n*D_INc + c];
            sumx += snA[n]; tsum += tv; tsq += tv*tv; cross += tv*snA[n];
        }
        const float inv = 1.f / (float)(NBb * Sc);
        float mean = (sumx + (float)Sc * tsum) * inv;
        float ex2  = (sumsq + 2.f*cross + (float)Sc * tsq) * inv;
        float var  = ex2 - mean*mean;
        float a = gamma[c] * rsqrtf(var + EPSV);
        aArr[c] = a;
        float b = beta[c];
        for (int n = 0; n < NBb; n++)
            offArr[n*D_INc + c] = (temb[n*D_INc + c] - mean) * a + b;
    }
}

// ---------------- K3: weight prep -> fragment-ordered bf16 ----------------
// wqfrag[(J=j>>4)*8 + kk=c>>5][lane=(j&15)+16*((c&31)>>3)][e=c&7], j in 0..1087 (q,k,v)
// wpfrag[(Ct=c>>4)*16 + kk=j'>>5][lane=(c&15)+16*((j'&31)>>3)][e=j'&7], val Wp[(j'&63)*8+(j'>>6)][c]
__global__ __launch_bounds__(256) void k_prepwb(const float* __restrict__ Wq,
        const float* __restrict__ Wk, const float* __restrict__ Wv,
        const float* __restrict__ Wp,
        __hip_bfloat16* __restrict__ wqfrag, __hip_bfloat16* __restrict__ wpfrag) {
    int b = blockIdx.x, t = threadIdx.x;
    if (b < 1088) {
        int j = b, c = t;
        float v;
        if (j < 512) v = Wq[c*D_KQc + j];
        else if (j < 1024) v = Wk[c*D_KQc + (j-512)];
        else v = Wv[c*D_Vc + (j-1024)];
        size_t fidx = (((size_t)(j>>4)*8 + (c>>5))*64 + ((j&15) + 16*((c&31)>>3)))*8 + (c&7);
        wqfrag[fidx] = __float2bfloat16(v);
    } else {
        int cout = b - 1088;
        for (int j = t; j < 512; j += 256) {
            int r = (j & 63)*8 + (j >> 6);
            float v = Wp[r*D_INc + cout];
            size_t fidx = (((size_t)(cout>>4)*16 + (j>>5))*64 + ((cout&15) + 16*((j&31)>>3)))*8 + (j&7);
            wpfrag[fidx] = __float2bfloat16(v);
        }
    }
}

// ---------------- K4: afrag = BN(x) transposed into QKV A-fragment order ----------------
// afrag[(n*64 + s>>4)*8 + kk=c>>5][lane=(s&15)+16*((c&31)>>3)][e=c&7]
__global__ __launch_bounds__(256) void k_xsb(const float* __restrict__ x,
        const float* __restrict__ aArr, const float* __restrict__ offArr,
        __hip_bfloat16* __restrict__ afrag) {
    __shared__ float tile[64][65];
    int s0 = blockIdx.x * 64, c0 = blockIdx.y * 64, n = blockIdx.z;
    int t = threadIdx.x;
    #pragma unroll
    for (int p = 0; p < 16; p++) {
        int idx = p*256 + t;
        int cl = idx >> 6, sl = idx & 63;
        int c = c0 + cl;
        tile[cl][sl] = x[((size_t)(n*D_INc + c))*Sc + s0 + sl] * aArr[c] + offArr[n*D_INc + c];
    }
    __syncthreads();
    #pragma unroll
    for (int p = 0; p < 16; p++) {
        int idx = p*256 + t;
        int sl = idx >> 6, cl = idx & 63;
        int s = s0 + sl, c = c0 + cl;
        size_t fidx = (((size_t)(n*64 + (s>>4))*8 + (c>>5))*64 + ((s&15) + 16*((c&31)>>3)))*8 + (c&7);
        afrag[fidx] = __float2bfloat16(tile[cl][sl]);
    }
}

// ---------------- K5: QKV bf16 MFMA, all operand loads coalesced ----------------
// Output: fragment-ordered Q/K/V for attention (verified epilogue, unchanged).
__global__ __launch_bounds__(256) void k_qkvb(const __hip_bfloat16* __restrict__ afrag,
        const __hip_bfloat16* __restrict__ wqfrag, __hip_bfloat16* __restrict__ qfrag,
        __hip_bfloat16* __restrict__ kfrag, __hip_bfloat16* __restrict__ vfrag) {
    int jt = blockIdx.x, st = blockIdx.y, n = blockIdx.z;
    int t = threadIdx.x, w = t >> 6, l = t & 63;
    int lr = l & 15, lg = l >> 4;
    int s0 = st*64, j0 = jt*64;
    int sT = st*4 + w;
    const bf16x8* A = reinterpret_cast<const bf16x8*>(afrag + ((size_t)(n*64 + sT)*8)*512) + l;
    const bf16x8* B = reinterpret_cast<const bf16x8*>(wqfrag + ((size_t)(jt*4)*8)*512) + l;
    f32x4 acc[4] = {};
    for (int kk = 0; kk < 8; kk++) {
        bf16x8 a = A[kk*64];
        #pragma unroll
        for (int nt = 0; nt < 4; nt++) {
            bf16x8 b = B[(nt*8 + kk)*64];
            acc[nt] = __builtin_amdgcn_mfma_f32_16x16x32_bf16(a, b, acc[nt], 0, 0, 0);
        }
    }
    const float QSC = 0.044194173824159216f * 1.4426950408889634f; // scale * log2(e)
    #pragma unroll
    for (int nt = 0; nt < 4; nt++) {
        #pragma unroll
        for (int r = 0; r < 4; r++) {
            int s = s0 + w*16 + lg*4 + r;          // token index
            int j = j0 + nt*16 + lr;               // output-feature index
            float v = acc[nt][r];
            if (j0 < 512) {
                int h = j >> 6, d = j & 63;
                size_t idx = ((((size_t)(n*8 + h)*64 + (s>>4))*2 + (d>>5))*64
                              + ((s&15) + 16*((d&31)>>3)))*8 + (d&7);
                qfrag[idx] = __float2bfloat16(v * QSC);
            } else if (j0 < 1024) {
                int jk = j - 512;
                int h = jk >> 6, d = jk & 63;
                size_t idx = ((((size_t)(n*8 + h)*64 + (s>>4))*2 + (d>>5))*64
                              + ((s&15) + 16*((d&31)>>3)))*8 + (d&7);
                kfrag[idx] = __float2bfloat16(v);
            } else {
                int dv = j - 1024;
                size_t idx = (((size_t)(n*32 + (s>>5))*4 + (dv>>4))*64
                              + ((dv&15) + 16*((s&31)>>3)))*8 + (s&7);
                vfrag[idx] = __float2bfloat16(v);
            }
        }
    }
}

// ---------------- K6: MFMA attention; epilogue writes proj-B fragment order ----------------
__global__ __launch_bounds__(256) void k_attnb(const __hip_bfloat16* __restrict__ qfrag,
        const __hip_bfloat16* __restrict__ kfrag, const __hip_bfloat16* __restrict__ vfrag,
        __hip_bfloat16* __restrict__ obfrag) {
    __shared__ float olds[4][16][68];
    int qt = blockIdx.x, h = blockIdx.y, n = blockIdx.z;
    int t = threadIdx.x, w = t >> 6, l = t & 63;
    int lr = l & 15, lg = l >> 4;
    int qb2 = qt*4 + w;                    // 16-q block index 0..63
    const __hip_bfloat16* qbase = qfrag + (((size_t)(n*8 + h)*64 + qb2)*2)*512 + l*8;
    bf16x8 qf0 = *reinterpret_cast<const bf16x8*>(qbase);
    bf16x8 qf1 = *reinterpret_cast<const bf16x8*>(qbase + 512);
    const __hip_bfloat16* kf = kfrag + ((size_t)(n*8 + h)*64)*1024 + l*8;  // per kb16: 1024 elems
    const __hip_bfloat16* vf = vfrag + (size_t)n*32*2048 + l*8;            // per kb32: 2048 elems
    float m = -1e30f, lsum = 0.f;
    f32x4 oacc[4] = {};
    for (int kc = 0; kc < 16; kc++) {
        f32x4 sa[4] = {};
        #pragma unroll
        for (int g = 0; g < 4; g++) {
            const __hip_bfloat16* kr = kf + (size_t)(kc*4 + g)*1024;
            bf16x8 klo = *reinterpret_cast<const bf16x8*>(kr);
            bf16x8 khi = *reinterpret_cast<const bf16x8*>(kr + 512);
            sa[g] = __builtin_amdgcn_mfma_f32_16x16x32_bf16(klo, qf0, sa[g], 0,0,0);
            sa[g] = __builtin_amdgcn_mfma_f32_16x16x32_bf16(khi, qf1, sa[g], 0,0,0);
        }
        float sv[16];
        #pragma unroll
        for (int g = 0; g < 4; g++)
            #pragma unroll
            for (int r = 0; r < 4; r++) sv[g*4 + r] = sa[g][r];
        float cmax = sv[0];
        #pragma unroll
        for (int i = 1; i < 16; i++) cmax = fmaxf(cmax, sv[i]);
        if (!__all(cmax <= m + 11.0f)) {   // defer-max
            cmax = fmaxf(cmax, __shfl_xor(cmax, 16));
            cmax = fmaxf(cmax, __shfl_xor(cmax, 32));
            float mnew = fmaxf(m, cmax);
            float sf = exp2f(m - mnew);
            lsum *= sf;
            #pragma unroll
            for (int mt = 0; mt < 4; mt++)
                #pragma unroll
                for (int r = 0; r < 4; r++) oacc[mt][r] *= sf;
            m = mnew;
        }
        float p[16];
        #pragma unroll
        for (int i = 0; i < 16; i++) { p[i] = exp2f(sv[i] - m); lsum += p[i]; }
        int srcA = lr + ((l & 16) ? 32 : 0);
        int srcB = srcA + 16;
        bool hi = (l & 32) != 0;
        #pragma unroll
        for (int half = 0; half < 2; half++) {
            unsigned int u00 = pack2(p[half*8+0], p[half*8+1]);
            unsigned int u01 = pack2(p[half*8+2], p[half*8+3]);
            unsigned int u10 = pack2(p[half*8+4], p[half*8+5]);
            unsigned int u11 = pack2(p[half*8+6], p[half*8+7]);
            unsigned int a0 = (unsigned int)__shfl((int)u00, srcA);
            unsigned int h0 = (unsigned int)__shfl((int)u10, srcA);
            unsigned int a1 = (unsigned int)__shfl((int)u01, srcA);
            unsigned int h1 = (unsigned int)__shfl((int)u11, srcA);
            unsigned int a2 = (unsigned int)__shfl((int)u00, srcB);
            unsigned int h2 = (unsigned int)__shfl((int)u10, srcB);
            unsigned int a3 = (unsigned int)__shfl((int)u01, srcB);
            unsigned int h3 = (unsigned int)__shfl((int)u11, srcB);
            uint4 pvu = { hi?h0:a0, hi?h1:a1, hi?h2:a2, hi?h3:a3 };
            bf16x8 pb = __builtin_bit_cast(bf16x8, pvu);
            const __hip_bfloat16* vblk = vf + (size_t)(kc*2 + half)*2048;
            #pragma unroll
            for (int mt = 0; mt < 4; mt++) {
                bf16x8 vfr = *reinterpret_cast<const bf16x8*>(vblk + mt*512);
                oacc[mt] = __builtin_amdgcn_mfma_f32_16x16x32_bf16(vfr, pb, oacc[mt], 0,0,0);
            }
        }
    }
    lsum += __shfl_xor(lsum, 16);
    lsum += __shfl_xor(lsum, 32);
    float inv = 1.f / lsum;
    #pragma unroll
    for (int mt = 0; mt < 4; mt++)
        #pragma unroll
        for (int r = 0; r < 4; r++)
            olds[w][lr][mt*16 + lg*4 + r] = oacc[mt][r] * inv;
    __syncthreads();
    // write proj-B fragments: obfrag[((n*64+sT)*16 + (h*2+half))*512 + l*8 + e]
    //   where s = sT*16 + (l&15), k-dim = h*64 + (32*half + (l>>4)*8 + e)
    #pragma unroll
    for (int half = 0; half < 2; half++) {
        const float* orow = &olds[w][l & 15][32*half + (l >> 4)*8];
        uint4 pk;
        pk.x = pack2(orow[0], orow[1]);
        pk.y = pack2(orow[2], orow[3]);
        pk.z = pack2(orow[4], orow[5]);
        pk.w = pack2(orow[6], orow[7]);
        *reinterpret_cast<uint4*>(obfrag
            + (((size_t)(n*64 + qb2)*16) + (h*2 + half))*512 + l*8) = pk;
    }
}

// ---------------- K7: proj MFMA, coalesced frag operands; +bias +residual ----------------
__global__ __launch_bounds__(256) void k_projb(const __hip_bfloat16* __restrict__ obfrag,
        const __hip_bfloat16* __restrict__ wpfrag, const float* __restrict__ bp,
        const float* __restrict__ x, float* __restrict__ out) {
    int st = blockIdx.x, ct = blockIdx.y, n = blockIdx.z;
    int t = threadIdx.x, w = t >> 6, l = t & 63;
    int lr = l & 15, lg = l >> 4;
    int s0 = st*64, c0 = ct*64 + w*16;
    int Ct = ct*4 + w;
    const bf16x8* A = reinterpret_cast<const bf16x8*>(wpfrag + ((size_t)Ct*16)*512) + l;
    const bf16x8* B = reinterpret_cast<const bf16x8*>(obfrag + ((size_t)(n*64 + st*4)*16)*512) + l;
    f32x4 acc[4] = {};
    for (int kk = 0; kk < 16; kk++) {
        bf16x8 a = A[kk*64];
        #pragma unroll
        for (int nt = 0; nt < 4; nt++) {
            bf16x8 b = B[(nt*16 + kk)*64];
            acc[nt] = __builtin_amdgcn_mfma_f32_16x16x32_bf16(a, b, acc[nt], 0,0,0);
        }
    }
    #pragma unroll
    for (int nt = 0; nt < 4; nt++) {
        #pragma unroll
        for (int r = 0; r < 4; r++) {
            int c = c0 + lg*4 + r;
            size_t idx = ((size_t)(n*D_INc + c))*Sc + s0 + nt*16 + lr;
            out[idx] = acc[nt][r] + bp[c] + x[idx];
        }
    }
}

extern "C" void kernel_launch(void* const* d_in, const int* in_sizes, int n_in,
                              void* d_out, int out_size, void* d_ws, size_t ws_size,
                              hipStream_t stream) {
    const float* x     = (const float*)d_in[0];
    const float* t     = (const float*)d_in[1];
    const float* Wt    = (const float*)d_in[2];
    const float* bt    = (const float*)d_in[3];
    const float* Wq    = (const float*)d_in[4];
    const float* Wk    = (const float*)d_in[5];
    const float* Wv    = (const float*)d_in[6];
    const float* Wp    = (const float*)d_in[7];
    const float* bp    = (const float*)d_in[8];
    const float* gamma = (const float*)d_in[9];
    const float* beta  = (const float*)d_in[10];
    char* ws = (char*)d_ws;
    float* temb  = (float*)(ws + 0);               // 8 KB
    float* aArr  = (float*)(ws + 8192);            // 1 KB
    float* offA  = (float*)(ws + 9216);            // 8 KB
    __hip_bfloat16* wqfrag = (__hip_bfloat16*)(ws + 32768);     // 544 KB
    __hip_bfloat16* wpfrag = (__hip_bfloat16*)(ws + 589824);    // 256 KB
    __hip_bfloat16* afrag  = (__hip_bfloat16*)(ws + 1048576);   // 4 MB
    __hip_bfloat16* qfrag  = (__hip_bfloat16*)(ws + 5242880);   // 8 MB
    __hip_bfloat16* kfrag  = (__hip_bfloat16*)(ws + 13631488);  // 8 MB
    __hip_bfloat16* vfrag  = (__hip_bfloat16*)(ws + 22020096);  // 1 MB
    __hip_bfloat16* obfrag = (__hip_bfloat16*)(ws + 23068672);  // 8 MB
    float* out = (float*)d_out;

    hipLaunchKernelGGL(k_temb,   dim3(8),        dim3(256), 0, stream, t, Wt, bt, temb);
    hipLaunchKernelGGL(k_stats,  dim3(256),      dim3(256), 0, stream, x, temb, gamma, beta, aArr, offA);
    hipLaunchKernelGGL(k_prepwb, dim3(1344),     dim3(256), 0, stream, Wq, Wk, Wv, Wp, wqfrag, wpfrag);
    hipLaunchKernelGGL(k_xsb,    dim3(16,4,8),   dim3(256), 0, stream, x, aArr, offA, afrag);
    hipLaunchKernelGGL(k_qkvb,   dim3(17,16,8),  dim3(256), 0, stream, afrag, wqfrag, qfrag, kfrag, vfrag);
    hipLaunchKernelGGL(k_attnb,  dim3(16,8,8),   dim3(256), 0, stream, qfrag, kfrag, vfrag, obfrag);
    hipLaunchKernelGGL(k_projb,  dim3(16,4,8),   dim3(256), 0, stream, obfrag, wpfrag, bp, x, out);
}